// Round 7
// baseline (186.027 us; speedup 1.0000x reference)
//
#include <hip/hip_runtime.h>
#include <hip/hip_bf16.h>

#define BATCH 65536
#define INF   64
#define OUTF  256
#define NMAT  15
#define RPB   256   // rows per block
#define NT    (RPB / 32)

typedef __bf16 bf16x8 __attribute__((ext_vector_type(8)));
typedef float  f32x4  __attribute__((ext_vector_type(4)));

__device__ __forceinline__ unsigned short f2bf(float f) {
    unsigned int u = __float_as_uint(f);
    unsigned int r = (u + 0x7FFFu + ((u >> 16) & 1u)) >> 16;
    return (unsigned short)r;
}

// Build combined bf16 weights wc[15][256][64] in streaming combine order:
// slot: 0=d1t, 1=d1_0, 2=M0, 3=d1_1, 4=M1, 5=M2, 6=d1_2, 7=M3, 8=M4, 9=M5,
//       10=d1_3, 11=M6, 12=M7, 13=M8, 14=M9   (M_p = dn_w2[p] * dn_w1[p][None,:])
__global__ void build_weights(const float* __restrict__ d1t_w,
                              const float* __restrict__ d1_w,
                              const float* __restrict__ dn_w1,
                              const float* __restrict__ dn_w2,
                              unsigned short* __restrict__ wc) {
    int idx = blockIdx.x * blockDim.x + threadIdx.x;
    if (idx >= NMAT * OUTF * INF) return;
    int slot = idx / (OUTF * INF);
    int rem  = idx - slot * (OUTF * INF);   // o*64 + i
    int i    = rem & (INF - 1);

    const signed char kind[NMAT] = {0,1,2,1,2,2,1,2,2,2,1,2,2,2,2};
    const signed char sidx[NMAT] = {0,0,0,1,1,2,2,3,4,5,3,6,7,8,9};

    int k = kind[slot], si = sidx[slot];
    float v;
    if (k == 0)      v = d1t_w[rem];
    else if (k == 1) v = d1_w[si * OUTF * INF + rem];
    else             v = dn_w2[si * OUTF * INF + rem] * dn_w1[si * INF + i];
    wc[idx] = f2bf(v);
}

// Register-resident weights, swapped MFMA operands (A = weights, B = x rows),
// prefetch depth 2: loads for tile t+2 are in flight across two full compute
// blocks (~1100+ cyc), covering HBM latency (~900 cyc) instead of the previous
// 1-tile distance that stalled every iteration.
__global__ __launch_bounds__(256, 2) void taylor_kernel(
    const float* __restrict__ x, const float* __restrict__ d0,
    const unsigned short* __restrict__ wc, float* __restrict__ out)
{
    const int lane = threadIdx.x & 63;
    const int wave = threadIdx.x >> 6;      // 0..3
    const int l15  = lane & 15;
    const int g    = lane >> 4;             // k-group 0..3
    const int cg   = blockIdx.x & 3;        // col-group (64 cols)
    const int rc   = blockIdx.x >> 2;       // row-chunk (RPB rows)
    const int colstrip = cg * 64 + wave * 16;

    // One-time A (weight) load: 15 mats x 2 k-slices, 8 bf16 each = 120 VGPR.
    bf16x8 b[NMAT][2];
#pragma unroll
    for (int w = 0; w < NMAT; ++w) {
        const unsigned short* wp = wc + ((size_t)w * OUTF + colstrip + l15) * INF + g * 8;
#pragma unroll
        for (int s = 0; s < 2; ++s)
            b[w][s] = *(const bf16x8*)(wp + s * 32);
    }
    const f32x4 d0v = *(const f32x4*)(d0 + colstrip + g * 4);

    // per-pass combine op: 0 = res=d0+y, 1 = tmp=y, 2 = tmp*=y, 3 = tmp*=y; res+=tmp
    constexpr int OPS[NMAT] = {0,1,3,1,2,3,1,2,2,3,1,2,2,2,3};
    const size_t row0 = (size_t)rc * RPB;

    auto issue = [&](f32x4 (&pf)[8], int it) {
#pragma unroll
        for (int rf = 0; rf < 2; ++rf) {
            const float* xp = x + (row0 + (size_t)it * 32 + rf * 16 + l15) * INF + g * 8;
#pragma unroll
            for (int s = 0; s < 2; ++s) {
                pf[rf * 4 + s * 2 + 0] = *(const f32x4*)(xp + s * 32);
                pf[rf * 4 + s * 2 + 1] = *(const f32x4*)(xp + s * 32 + 4);
            }
        }
    };

    auto cvt = [&](f32x4 (&pf)[8], bf16x8 (&a)[2][2]) {
#pragma unroll
        for (int rf = 0; rf < 2; ++rf)
#pragma unroll
            for (int s = 0; s < 2; ++s) {
                f32x4 v0 = pf[rf * 4 + s * 2], v1 = pf[rf * 4 + s * 2 + 1];
                bf16x8 fr;
#pragma unroll
                for (int j = 0; j < 4; ++j) { fr[j] = (__bf16)v0[j]; fr[4 + j] = (__bf16)v1[j]; }
                a[rf][s] = fr;
            }
    };

    auto compute_store = [&](bf16x8 (&a)[2][2], int it) {
        f32x4 res[2], tmp[2];
#pragma unroll
        for (int w = 0; w < NMAT; ++w) {
#pragma unroll
            for (int rf = 0; rf < 2; ++rf) {
                f32x4 c0 = (OPS[w] == 0) ? d0v : f32x4{0.f, 0.f, 0.f, 0.f};
                f32x4 y;
                y = __builtin_amdgcn_mfma_f32_16x16x32_bf16(b[w][0], a[rf][0], c0, 0, 0, 0);
                y = __builtin_amdgcn_mfma_f32_16x16x32_bf16(b[w][1], a[rf][1], y, 0, 0, 0);
                if (OPS[w] == 0) {
                    res[rf] = y;
                } else if (OPS[w] == 1) {
                    tmp[rf] = y;
                } else {
                    tmp[rf] = tmp[rf] * y;
                    if (OPS[w] == 3) res[rf] = res[rf] + tmp[rf];
                }
            }
        }
        const size_t rbase = row0 + (size_t)it * 32;
#pragma unroll
        for (int rf = 0; rf < 2; ++rf) {
            float* op = out + (rbase + rf * 16 + l15) * OUTF + colstrip + g * 4;
            *(f32x4*)op = res[rf];
        }
    };

    f32x4 p0[8], p1[8];
    issue(p0, 0);
    issue(p1, 1);

#pragma unroll 1
    for (int it = 0; it < NT; it += 2) {
        bf16x8 a[2][2];
        cvt(p0, a);
        if (it + 2 < NT) issue(p0, it + 2);
        compute_store(a, it);
        cvt(p1, a);
        if (it + 3 < NT) issue(p1, it + 3);
        compute_store(a, it + 1);
    }
}

extern "C" void kernel_launch(void* const* d_in, const int* in_sizes, int n_in,
                              void* d_out, int out_size, void* d_ws, size_t ws_size,
                              hipStream_t stream) {
    const float* x    = (const float*)d_in[0];
    const float* d0   = (const float*)d_in[1];
    const float* d1t  = (const float*)d_in[2];
    const float* d1w  = (const float*)d_in[3];
    const float* dnw1 = (const float*)d_in[4];
    const float* dnw2 = (const float*)d_in[5];
    unsigned short* wc = (unsigned short*)d_ws;   // 480 KiB
    float* out = (float*)d_out;

    build_weights<<<(NMAT * OUTF * INF + 255) / 256, 256, 0, stream>>>(d1t, d1w, dnw1, dnw2, wc);
    taylor_kernel<<<4 * (BATCH / RPB), 256, 0, stream>>>(x, d0, wc, out);
}

// Round 8
// 60.932 us; speedup vs baseline: 3.0530x; 3.0530x over previous
//
#include <hip/hip_runtime.h>
#include <hip/hip_bf16.h>

#define BATCH 65536
#define INF   64
#define OUTF  256
#define NMAT  15
#define RPB   256          // rows per block
#define NT    (RPB / 32)   // 8 tiles of 32 rows

typedef __bf16 bf16x8 __attribute__((ext_vector_type(8)));
typedef float  f32x4  __attribute__((ext_vector_type(4)));

__device__ __forceinline__ unsigned short f2bf(float f) {
    unsigned int u = __float_as_uint(f);
    unsigned int r = (u + 0x7FFFu + ((u >> 16) & 1u)) >> 16;
    return (unsigned short)r;
}

// Fused prep: (a) convert x fp32->bf16 (every thread, 8 elems), (b) build the
// 15 combined bf16 weight mats (first 30720 threads, 8 elems each).
// slot order: 0=d1t, 1=d1_0, 2=M0, 3=d1_1, 4=M1, 5=M2, 6=d1_2, 7=M3, 8=M4,
// 9=M5, 10=d1_3, 11=M6, 12=M7, 13=M8, 14=M9  (M_p = dn_w2[p]*dn_w1[p][None,:])
__global__ void prep(const float* __restrict__ x,
                     const float* __restrict__ d1t_w,
                     const float* __restrict__ d1_w,
                     const float* __restrict__ dn_w1,
                     const float* __restrict__ dn_w2,
                     unsigned short* __restrict__ wc,
                     unsigned short* __restrict__ xb) {
    const int idx = blockIdx.x * 256 + threadIdx.x;   // grid = 2048 blocks exactly

    {   // x conversion: 524288 threads * 8 = 4194304 elems, exact cover
        const float* xp = x + (size_t)idx * 8;
        f32x4 v0 = *(const f32x4*)xp;
        f32x4 v1 = *(const f32x4*)(xp + 4);
        bf16x8 fr;
#pragma unroll
        for (int j = 0; j < 4; ++j) { fr[j] = (__bf16)v0[j]; fr[4 + j] = (__bf16)v1[j]; }
        *(bf16x8*)(xb + (size_t)idx * 8) = fr;
    }

    if (idx < NMAT * OUTF * INF / 8) {                // 30720 weight threads
        const signed char kind[NMAT] = {0,1,2,1,2,2,1,2,2,2,1,2,2,2,2};
        const signed char sidx[NMAT] = {0,0,0,1,1,2,2,3,4,5,3,6,7,8,9};
        const int slot = idx >> 11;                   // / 2048
        const int rem  = (idx & 2047) * 8;            // o*64 + i, 8-aligned
        const int i0   = rem & (INF - 1);
        const int k = kind[slot], si = sidx[slot];
        unsigned short o8[8];
#pragma unroll
        for (int j = 0; j < 8; ++j) {
            float v;
            if (k == 0)      v = d1t_w[rem + j];
            else if (k == 1) v = d1_w[si * OUTF * INF + rem + j];
            else             v = dn_w2[si * OUTF * INF + rem + j] * dn_w1[si * INF + i0 + j];
            o8[j] = f2bf(v);
        }
        *(bf16x8*)(wc + (size_t)slot * OUTF * INF + rem) = *(bf16x8*)o8;
    }
}

// One 32-row x-tile for one wave: rf0/rf1 are row blocks, s0/s1 are k-halves.
// Named members (NOT an array) so nothing can be demoted to scratch.
struct Tile { bf16x8 v00, v01, v10, v11; };

__device__ __forceinline__ void issue_tile(const unsigned short* __restrict__ p, Tile& d) {
    d.v00 = *(const bf16x8*)(p);                 // rf0, s0
    d.v01 = *(const bf16x8*)(p + 32);            // rf0, s1
    d.v10 = *(const bf16x8*)(p + 16 * INF);      // rf1, s0
    d.v11 = *(const bf16x8*)(p + 16 * INF + 32); // rf1, s1
}

// Register-resident weights; swapped MFMA operands (A = weights, B = x rows):
// lane holds 4 consecutive out-cols of one batch row -> coalesced dwordx4 store.
// 3-buffer rotation: load for tile t+2 issued at start of step t -> ~2 compute
// blocks of latency coverage, with zero scratch (all buffers named).
__global__ __launch_bounds__(256) void taylor_kernel(
    const unsigned short* __restrict__ xb, const float* __restrict__ d0,
    const unsigned short* __restrict__ wc, float* __restrict__ out)
{
    const int lane = threadIdx.x & 63;
    const int wave = threadIdx.x >> 6;      // 0..3
    const int l15  = lane & 15;
    const int g    = lane >> 4;             // k-group 0..3
    // x-sharing blocks on same XCD: sharers of row-chunk rc are bids
    // {rc, rc+256, rc+512, rc+768}, all == rc (mod 8).
    const int cg   = blockIdx.x >> 8;       // col-group (64 cols)
    const int rc   = blockIdx.x & 255;      // row-chunk (RPB rows)
    const int colstrip = cg * 64 + wave * 16;

    // One-time A (weight) load: 15 mats x 2 k-slices = 120 VGPR.
    // A-frag: row = lane&15 (out-col in strip), k = (lane>>4)*8 + j.
    bf16x8 b[NMAT][2];
#pragma unroll
    for (int w = 0; w < NMAT; ++w) {
        const unsigned short* wp = wc + ((size_t)w * OUTF + colstrip + l15) * INF + g * 8;
#pragma unroll
        for (int s = 0; s < 2; ++s)
            b[w][s] = *(const bf16x8*)(wp + s * 32);
    }
    const f32x4 d0v = *(const f32x4*)(d0 + colstrip + g * 4);

    constexpr int OPS[NMAT] = {0,1,3,1,2,3,1,2,2,3,1,2,2,2,3};
    const size_t row0 = (size_t)rc * RPB;
    const unsigned short* xlane = xb + (row0 + l15) * INF + g * 8;

    auto cs = [&](const Tile& U, int t) {
        f32x4 res0, res1, tmp0, tmp1;
#pragma unroll
        for (int w = 0; w < NMAT; ++w) {
            f32x4 c0 = (OPS[w] == 0) ? d0v : f32x4{0.f, 0.f, 0.f, 0.f};
            f32x4 y0 = __builtin_amdgcn_mfma_f32_16x16x32_bf16(b[w][0], U.v00, c0, 0, 0, 0);
            y0       = __builtin_amdgcn_mfma_f32_16x16x32_bf16(b[w][1], U.v01, y0, 0, 0, 0);
            f32x4 y1 = __builtin_amdgcn_mfma_f32_16x16x32_bf16(b[w][0], U.v10, c0, 0, 0, 0);
            y1       = __builtin_amdgcn_mfma_f32_16x16x32_bf16(b[w][1], U.v11, y1, 0, 0, 0);
            if (OPS[w] == 0)      { res0 = y0; res1 = y1; }
            else if (OPS[w] == 1) { tmp0 = y0; tmp1 = y1; }
            else {
                tmp0 = tmp0 * y0; tmp1 = tmp1 * y1;
                if (OPS[w] == 3) { res0 = res0 + tmp0; res1 = res1 + tmp1; }
            }
        }
        const size_t rbase = row0 + (size_t)t * 32;
        float* op0 = out + (rbase + l15) * OUTF + colstrip + g * 4;
        float* op1 = out + (rbase + 16 + l15) * OUTF + colstrip + g * 4;
        *(f32x4*)op0 = res0;
        *(f32x4*)op1 = res1;
    };

    Tile A, B, C;
    issue_tile(xlane + (size_t)0 * 32 * INF, A);
    issue_tile(xlane + (size_t)1 * 32 * INF, B);

    issue_tile(xlane + (size_t)2 * 32 * INF, C); cs(A, 0);
    issue_tile(xlane + (size_t)3 * 32 * INF, A); cs(B, 1);
    issue_tile(xlane + (size_t)4 * 32 * INF, B); cs(C, 2);
    issue_tile(xlane + (size_t)5 * 32 * INF, C); cs(A, 3);
    issue_tile(xlane + (size_t)6 * 32 * INF, A); cs(B, 4);
    issue_tile(xlane + (size_t)7 * 32 * INF, B); cs(C, 5);
    cs(A, 6);
    cs(B, 7);
}

// Fallback (ws too small): R6-style fp32-x kernel, depth-1.
__global__ __launch_bounds__(256) void taylor_f32(
    const float* __restrict__ x, const float* __restrict__ d0,
    const unsigned short* __restrict__ wc, float* __restrict__ out)
{
    const int lane = threadIdx.x & 63;
    const int wave = threadIdx.x >> 6;
    const int l15  = lane & 15;
    const int g    = lane >> 4;
    const int cg   = blockIdx.x & 3;
    const int rc   = blockIdx.x >> 2;
    const int colstrip = cg * 64 + wave * 16;

    bf16x8 b[NMAT][2];
#pragma unroll
    for (int w = 0; w < NMAT; ++w) {
        const unsigned short* wp = wc + ((size_t)w * OUTF + colstrip + l15) * INF + g * 8;
#pragma unroll
        for (int s = 0; s < 2; ++s)
            b[w][s] = *(const bf16x8*)(wp + s * 32);
    }
    const f32x4 d0v = *(const f32x4*)(d0 + colstrip + g * 4);
    constexpr int OPS[NMAT] = {0,1,3,1,2,3,1,2,2,3,1,2,2,2,3};
    const size_t row0 = (size_t)rc * RPB;

#pragma unroll 1
    for (int it = 0; it < NT; ++it) {
        bf16x8 a00, a01, a10, a11;
        {
            const float* xp0 = x + (row0 + (size_t)it * 32 + l15) * INF + g * 8;
            const float* xp1 = xp0 + 16 * INF;
            f32x4 u0, u1; bf16x8 fr;
#define CVT8(dst, p0) { u0 = *(const f32x4*)(p0); u1 = *(const f32x4*)((p0) + 4); \
            for (int j = 0; j < 4; ++j) { fr[j] = (__bf16)u0[j]; fr[4+j] = (__bf16)u1[j]; } dst = fr; }
            CVT8(a00, xp0); CVT8(a01, xp0 + 32); CVT8(a10, xp1); CVT8(a11, xp1 + 32);
#undef CVT8
        }
        f32x4 res0, res1, tmp0, tmp1;
#pragma unroll
        for (int w = 0; w < NMAT; ++w) {
            f32x4 c0 = (OPS[w] == 0) ? d0v : f32x4{0.f, 0.f, 0.f, 0.f};
            f32x4 y0 = __builtin_amdgcn_mfma_f32_16x16x32_bf16(b[w][0], a00, c0, 0, 0, 0);
            y0       = __builtin_amdgcn_mfma_f32_16x16x32_bf16(b[w][1], a01, y0, 0, 0, 0);
            f32x4 y1 = __builtin_amdgcn_mfma_f32_16x16x32_bf16(b[w][0], a10, c0, 0, 0, 0);
            y1       = __builtin_amdgcn_mfma_f32_16x16x32_bf16(b[w][1], a11, y1, 0, 0, 0);
            if (OPS[w] == 0)      { res0 = y0; res1 = y1; }
            else if (OPS[w] == 1) { tmp0 = y0; tmp1 = y1; }
            else {
                tmp0 = tmp0 * y0; tmp1 = tmp1 * y1;
                if (OPS[w] == 3) { res0 = res0 + tmp0; res1 = res1 + tmp1; }
            }
        }
        const size_t rbase = row0 + (size_t)it * 32;
        *(f32x4*)(out + (rbase + l15) * OUTF + colstrip + g * 4) = res0;
        *(f32x4*)(out + (rbase + 16 + l15) * OUTF + colstrip + g * 4) = res1;
    }
}

__global__ void build_weights_only(const float* __restrict__ d1t_w,
                                   const float* __restrict__ d1_w,
                                   const float* __restrict__ dn_w1,
                                   const float* __restrict__ dn_w2,
                                   unsigned short* __restrict__ wc) {
    int idx = blockIdx.x * blockDim.x + threadIdx.x;
    if (idx >= NMAT * OUTF * INF) return;
    int slot = idx / (OUTF * INF);
    int rem  = idx - slot * (OUTF * INF);
    int i    = rem & (INF - 1);
    const signed char kind[NMAT] = {0,1,2,1,2,2,1,2,2,2,1,2,2,2,2};
    const signed char sidx[NMAT] = {0,0,0,1,1,2,2,3,4,5,3,6,7,8,9};
    int k = kind[slot], si = sidx[slot];
    float v;
    if (k == 0)      v = d1t_w[rem];
    else if (k == 1) v = d1_w[si * OUTF * INF + rem];
    else             v = dn_w2[si * OUTF * INF + rem] * dn_w1[si * INF + i];
    wc[idx] = f2bf(v);
}

extern "C" void kernel_launch(void* const* d_in, const int* in_sizes, int n_in,
                              void* d_out, int out_size, void* d_ws, size_t ws_size,
                              hipStream_t stream) {
    const float* x    = (const float*)d_in[0];
    const float* d0   = (const float*)d_in[1];
    const float* d1t  = (const float*)d_in[2];
    const float* d1w  = (const float*)d_in[3];
    const float* dnw1 = (const float*)d_in[4];
    const float* dnw2 = (const float*)d_in[5];
    unsigned short* wc = (unsigned short*)d_ws;                 // 480 KiB
    float* out = (float*)d_out;

    const size_t XB_OFF   = 512 * 1024;
    const size_t XB_BYTES = (size_t)BATCH * INF * 2;            // 8 MiB
    if (ws_size >= XB_OFF + XB_BYTES) {
        unsigned short* xb = (unsigned short*)((char*)d_ws + XB_OFF);
        prep<<<BATCH * INF / 8 / 256, 256, 0, stream>>>(x, d1t, d1w, dnw1, dnw2, wc, xb);
        taylor_kernel<<<4 * (BATCH / RPB), 256, 0, stream>>>(xb, d0, wc, out);
    } else {
        build_weights_only<<<(NMAT * OUTF * INF + 255) / 256, 256, 0, stream>>>(d1t, d1w, dnw1, dnw2, wc);
        taylor_f32<<<4 * (BATCH / RPB), 256, 0, stream>>>(x, d0, wc, out);
    }
}

// Round 9
// 52.585 us; speedup vs baseline: 3.5377x; 1.1587x over previous
//
#include <hip/hip_runtime.h>
#include <hip/hip_bf16.h>

#define BATCH 65536
#define INF   64
#define OUTF  256
#define NMAT  15
#define RPB   256          // rows per block
#define NT    (RPB / 32)   // 8 tiles of 32 rows

typedef __bf16 bf16x8 __attribute__((ext_vector_type(8)));
typedef float  f32x4  __attribute__((ext_vector_type(4)));

__device__ __forceinline__ unsigned short f2bf(float f) {
    unsigned int u = __float_as_uint(f);
    unsigned int r = (u + 0x7FFFu + ((u >> 16) & 1u)) >> 16;
    return (unsigned short)r;
}

// ---------------------------------------------------------------------------
// Swizzled layouts (fragment-contiguous so every wave memory op is one
// contiguous 1-KB transaction):
//   xs: per 16-row group grp: byte = grp*2048 + s*1024 + g*256 + r*16
//       (r = row&15, k = s*32 + g*8 + j)  -> main-kernel lane (= g*16+r)
//       loads exactly  base + lane*16.
//   wcs: per (mat w, col-strip cs of 16 out-cols): byte =
//       ((w*16+cs)*2+s)*1024 + g*256 + l15*16.
// ---------------------------------------------------------------------------

// Fused prep (2048 blocks x 256): (a) x fp32 -> bf16 swizzled, (b) build the
// 15 combined weight mats swizzled. slot order: 0=d1t, 1=d1_0, 2=M0, 3=d1_1,
// 4=M1, 5=M2, 6=d1_2, 7=M3, 8=M4, 9=M5, 10=d1_3, 11=M6, 12=M7, 13=M8, 14=M9
// (M_p = dn_w2[p] * dn_w1[p][None,:])
__global__ void prep(const float* __restrict__ x,
                     const float* __restrict__ d1t_w,
                     const float* __restrict__ d1_w,
                     const float* __restrict__ dn_w1,
                     const float* __restrict__ dn_w2,
                     unsigned short* __restrict__ wcs,
                     unsigned short* __restrict__ xs) {
    const int idx = blockIdx.x * 256 + threadIdx.x;   // one 16-B chunk each

    {   // x: chunk idx covers row = idx>>3, elems cc*8..cc*8+7
        const int row = idx >> 3, cc = idx & 7;
        const int s = cc >> 2, g = cc & 3;
        const int grp = row >> 4, r = row & 15;
        const float* xp = x + (size_t)row * INF + cc * 8;
        f32x4 v0 = *(const f32x4*)xp;
        f32x4 v1 = *(const f32x4*)(xp + 4);
        bf16x8 fr;
#pragma unroll
        for (int j = 0; j < 4; ++j) { fr[j] = (__bf16)v0[j]; fr[4 + j] = (__bf16)v1[j]; }
        *(bf16x8*)((char*)xs + (size_t)grp * 2048 + s * 1024 + g * 256 + r * 16) = fr;
    }

    if (idx < NMAT * OUTF * INF / 8) {
        const signed char kind[NMAT] = {0,1,2,1,2,2,1,2,2,2,1,2,2,2,2};
        const signed char sidx[NMAT] = {0,0,0,1,1,2,2,3,4,5,3,6,7,8,9};
        const int slot = idx >> 11, rem8 = idx & 2047;
        const int o = rem8 >> 3, cc = rem8 & 7;       // out index, chunk-in-row
        const int s = cc >> 2, g = cc & 3;
        const int i0 = cc * 8;
        const int cs = o >> 4, l = o & 15;
        const int k = kind[slot], si = sidx[slot];
        unsigned short o8[8];
#pragma unroll
        for (int j = 0; j < 8; ++j) {
            const int e = o * INF + i0 + j;
            float v;
            if (k == 0)      v = d1t_w[e];
            else if (k == 1) v = d1_w[si * OUTF * INF + e];
            else             v = dn_w2[si * OUTF * INF + e] * dn_w1[si * INF + i0 + j];
            o8[j] = f2bf(v);
        }
        char* dst = (char*)wcs + (((size_t)slot * 16 + cs) * 2 + s) * 1024 + g * 256 + l * 16;
        *(bf16x8*)dst = *(bf16x8*)o8;
    }
}

struct Tile { bf16x8 v00, v01, v10, v11; };   // named members: no scratch demotion

#define LDS_W 68   // 64 cols + 4 pad floats -> even bank spread, 16-B aligned rows

__global__ __launch_bounds__(256) void taylor_kernel(
    const unsigned short* __restrict__ xs, const float* __restrict__ d0,
    const unsigned short* __restrict__ wcs, float* __restrict__ out)
{
    __shared__ float sbuf[2][32 * LDS_W];

    const int lane = threadIdx.x & 63;
    const int wave = threadIdx.x >> 6;      // 0..3
    const int l15  = lane & 15;
    const int g    = lane >> 4;
    // sharers of one row-chunk are bids {rc, rc+256, rc+512, rc+768}: same XCD
    const int cg   = blockIdx.x >> 8;       // col-group (64 cols)
    const int rc   = blockIdx.x & 255;      // row-chunk (RPB rows)
    const int cs   = cg * 4 + wave;         // 16-col strip id
    const int colstrip = cs * 16;

    // Weight prologue: 30 contiguous 1-KB loads (lane*16 within each page).
    bf16x8 b[NMAT][2];
    const char* wbase = (const char*)wcs + (size_t)cs * 2048 + lane * 16;
#pragma unroll
    for (int w = 0; w < NMAT; ++w)
#pragma unroll
        for (int s = 0; s < 2; ++s)
            b[w][s] = *(const bf16x8*)(wbase + (size_t)w * 32768 + s * 1024);

    const f32x4 d0v = *(const f32x4*)(d0 + colstrip + g * 4);

    constexpr int OPS[NMAT] = {0,1,3,1,2,3,1,2,2,3,1,2,2,2,3};
    const size_t row0 = (size_t)rc * RPB;
    const char* xbase = (const char*)xs + (row0 >> 4) * 2048 + lane * 16;

    auto issue = [&](Tile& T, int t) {   // 4 contiguous 1-KB loads
        const char* p = xbase + (size_t)t * 4096;
        T.v00 = *(const bf16x8*)(p);
        T.v01 = *(const bf16x8*)(p + 1024);
        T.v10 = *(const bf16x8*)(p + 2048);
        T.v11 = *(const bf16x8*)(p + 3072);
    };

    auto cs_fn = [&](const Tile& U, int t) {
        f32x4 res0, res1, tmp0, tmp1;
#pragma unroll
        for (int w = 0; w < NMAT; ++w) {
            f32x4 c0 = (OPS[w] == 0) ? d0v : f32x4{0.f, 0.f, 0.f, 0.f};
            f32x4 y0 = __builtin_amdgcn_mfma_f32_16x16x32_bf16(b[w][0], U.v00, c0, 0, 0, 0);
            y0       = __builtin_amdgcn_mfma_f32_16x16x32_bf16(b[w][1], U.v01, y0, 0, 0, 0);
            f32x4 y1 = __builtin_amdgcn_mfma_f32_16x16x32_bf16(b[w][0], U.v10, c0, 0, 0, 0);
            y1       = __builtin_amdgcn_mfma_f32_16x16x32_bf16(b[w][1], U.v11, y1, 0, 0, 0);
            if (OPS[w] == 0)      { res0 = y0; res1 = y1; }
            else if (OPS[w] == 1) { tmp0 = y0; tmp1 = y1; }
            else {
                tmp0 = tmp0 * y0; tmp1 = tmp1 * y1;
                if (OPS[w] == 3) { res0 = res0 + tmp0; res1 = res1 + tmp1; }
            }
        }
        // LDS transpose: frag (row=l15/l15+16, cols wave*16+g*4..+3) -> [32][68]
        float* sb = sbuf[t & 1];
        const int colw = wave * 16 + g * 4;
        *(f32x4*)&sb[l15 * LDS_W + colw]        = res0;
        *(f32x4*)&sb[(16 + l15) * LDS_W + colw] = res1;
        __syncthreads();
        // coalesced store: each wave-inst = 4 rows x 256 B (full lines)
        const size_t rbase = row0 + (size_t)t * 32;
#pragma unroll
        for (int j = 0; j < 2; ++j) {
            const int row = wave * 8 + j * 4 + g;
            const int cw  = l15 * 4;
            f32x4 v = *(const f32x4*)&sb[row * LDS_W + cw];
            *(f32x4*)(out + (rbase + row) * OUTF + cg * 64 + cw) = v;
        }
    };

    Tile A, B;
    issue(A, 0); issue(B, 1);
    cs_fn(A, 0); issue(A, 2);
    cs_fn(B, 1); issue(B, 3);
    cs_fn(A, 2); issue(A, 4);
    cs_fn(B, 3); issue(B, 5);
    cs_fn(A, 4); issue(A, 6);
    cs_fn(B, 5); issue(B, 7);
    cs_fn(A, 6);
    cs_fn(B, 7);
}

// ---------------- fallback path (ws too small): R6-style fp32 kernel --------
__global__ void build_weights_only(const float* __restrict__ d1t_w,
                                   const float* __restrict__ d1_w,
                                   const float* __restrict__ dn_w1,
                                   const float* __restrict__ dn_w2,
                                   unsigned short* __restrict__ wc) {
    int idx = blockIdx.x * blockDim.x + threadIdx.x;
    if (idx >= NMAT * OUTF * INF) return;
    int slot = idx / (OUTF * INF);
    int rem  = idx - slot * (OUTF * INF);
    int i    = rem & (INF - 1);
    const signed char kind[NMAT] = {0,1,2,1,2,2,1,2,2,2,1,2,2,2,2};
    const signed char sidx[NMAT] = {0,0,0,1,1,2,2,3,4,5,3,6,7,8,9};
    int k = kind[slot], si = sidx[slot];
    float v;
    if (k == 0)      v = d1t_w[rem];
    else if (k == 1) v = d1_w[si * OUTF * INF + rem];
    else             v = dn_w2[si * OUTF * INF + rem] * dn_w1[si * INF + i];
    wc[idx] = f2bf(v);
}

__global__ __launch_bounds__(256) void taylor_f32(
    const float* __restrict__ x, const float* __restrict__ d0,
    const unsigned short* __restrict__ wc, float* __restrict__ out)
{
    const int lane = threadIdx.x & 63;
    const int wave = threadIdx.x >> 6;
    const int l15  = lane & 15;
    const int g    = lane >> 4;
    const int cg   = blockIdx.x & 3;
    const int rc   = blockIdx.x >> 2;
    const int colstrip = cg * 64 + wave * 16;

    bf16x8 b[NMAT][2];
#pragma unroll
    for (int w = 0; w < NMAT; ++w) {
        const unsigned short* wp = wc + ((size_t)w * OUTF + colstrip + l15) * INF + g * 8;
#pragma unroll
        for (int s = 0; s < 2; ++s)
            b[w][s] = *(const bf16x8*)(wp + s * 32);
    }
    const f32x4 d0v = *(const f32x4*)(d0 + colstrip + g * 4);
    constexpr int OPS[NMAT] = {0,1,3,1,2,3,1,2,2,3,1,2,2,2,3};
    const size_t row0 = (size_t)rc * RPB;

#pragma unroll 1
    for (int it = 0; it < NT; ++it) {
        bf16x8 a00, a01, a10, a11;
        {
            const float* xp0 = x + (row0 + (size_t)it * 32 + l15) * INF + g * 8;
            const float* xp1 = xp0 + 16 * INF;
            f32x4 u0, u1; bf16x8 fr;
#define CVT8(dst, p0) { u0 = *(const f32x4*)(p0); u1 = *(const f32x4*)((p0) + 4); \
            for (int j = 0; j < 4; ++j) { fr[j] = (__bf16)u0[j]; fr[4+j] = (__bf16)u1[j]; } dst = fr; }
            CVT8(a00, xp0); CVT8(a01, xp0 + 32); CVT8(a10, xp1); CVT8(a11, xp1 + 32);
#undef CVT8
        }
        f32x4 res0, res1, tmp0, tmp1;
#pragma unroll
        for (int w = 0; w < NMAT; ++w) {
            f32x4 c0 = (OPS[w] == 0) ? d0v : f32x4{0.f, 0.f, 0.f, 0.f};
            f32x4 y0 = __builtin_amdgcn_mfma_f32_16x16x32_bf16(b[w][0], a00, c0, 0, 0, 0);
            y0       = __builtin_amdgcn_mfma_f32_16x16x32_bf16(b[w][1], a01, y0, 0, 0, 0);
            f32x4 y1 = __builtin_amdgcn_mfma_f32_16x16x32_bf16(b[w][0], a10, c0, 0, 0, 0);
            y1       = __builtin_amdgcn_mfma_f32_16x16x32_bf16(b[w][1], a11, y1, 0, 0, 0);
            if (OPS[w] == 0)      { res0 = y0; res1 = y1; }
            else if (OPS[w] == 1) { tmp0 = y0; tmp1 = y1; }
            else {
                tmp0 = tmp0 * y0; tmp1 = tmp1 * y1;
                if (OPS[w] == 3) { res0 = res0 + tmp0; res1 = res1 + tmp1; }
            }
        }
        const size_t rbase = row0 + (size_t)it * 32;
        *(f32x4*)(out + (rbase + l15) * OUTF + colstrip + g * 4) = res0;
        *(f32x4*)(out + (rbase + 16 + l15) * OUTF + colstrip + g * 4) = res1;
    }
}

extern "C" void kernel_launch(void* const* d_in, const int* in_sizes, int n_in,
                              void* d_out, int out_size, void* d_ws, size_t ws_size,
                              hipStream_t stream) {
    const float* x    = (const float*)d_in[0];
    const float* d0   = (const float*)d_in[1];
    const float* d1t  = (const float*)d_in[2];
    const float* d1w  = (const float*)d_in[3];
    const float* dnw1 = (const float*)d_in[4];
    const float* dnw2 = (const float*)d_in[5];
    unsigned short* wc = (unsigned short*)d_ws;                 // 480 KiB (swizzled)
    float* out = (float*)d_out;

    const size_t XB_OFF   = 512 * 1024;
    const size_t XB_BYTES = (size_t)BATCH * INF * 2;            // 8 MiB
    if (ws_size >= XB_OFF + XB_BYTES) {
        unsigned short* xs = (unsigned short*)((char*)d_ws + XB_OFF);
        prep<<<BATCH * INF / 8 / 256, 256, 0, stream>>>(x, d1t, d1w, dnw1, dnw2, wc, xs);
        taylor_kernel<<<4 * (BATCH / RPB), 256, 0, stream>>>(xs, d0, wc, out);
    } else {
        build_weights_only<<<(NMAT * OUTF * INF + 255) / 256, 256, 0, stream>>>(d1t, d1w, dnw1, dnw2, wc);
        taylor_f32<<<4 * (BATCH / RPB), 256, 0, stream>>>(x, d0, wc, out);
    }
}